// Round 4
// baseline (123.570 us; speedup 1.0000x reference)
//
#include <hip/hip_runtime.h>

#define N 4096
#define BLK 256
#define NEGF (-3.4e38f)

// 4B-aligned float4 (multi-dword global loads need only dword alignment on CDNA).
typedef float f4u __attribute__((ext_vector_type(4), aligned(4)));
typedef float f4a __attribute__((ext_vector_type(4), aligned(16)));

// Single-pass, two running maxes per row (mask is exactly {0,1}):
//   bc = max over {m=1} of score     (ref's global min is dead code)
//   sm = max over {m=0, j<row} of ana score
//   loss = max(0, rc*(1+sm-bc), (d==0)*fn*(1+eps-bc))
// R4 = R2 (best measured) + NONTEMPORAL streaming loads only.
// Rationale: the harness's 2x256MiB poison fills leave the entire 256MiB LLC
// dirty; regular reads allocate -> evict dirty victims -> forced HBM
// writebacks roughly doubling kernel traffic. nt loads skip allocation.
__global__ __launch_bounds__(BLK) void mention_loss_kernel(
    const float* __restrict__ eps_scores,
    const float* __restrict__ ana_scores,
    const float* __restrict__ mask,
    const float* __restrict__ link_costs,
    const float* __restrict__ false_new_cost,
    float* __restrict__ out)
{
    // Longest rows first: blockIdx 0 -> row N-1.
    const int row = N - 1 - (int)blockIdx.x;
    const int tid = threadIdx.x;
    const long long base = (long long)row * (row - 1) / 2;
    const float* __restrict__ arow = ana_scores + base;
    const float* __restrict__ mrow = mask + (size_t)row * (size_t)N;

    float bc0 = NEGF, bc1 = NEGF, bc2 = NEGF, bc3 = NEGF;
    float sm0 = NEGF, sm1 = NEGF, sm2 = NEGF, sm3 = NEGF;

    // Peel so ana_scores + base + p is 16B-aligned.
    int p = (int)((4 - (base & 3)) & 3);
    if (p > row) p = row;
    const int nvec = (row - p) >> 2;          // float4 groups in [p, p+4*nvec)
    const int t0   = p + (nvec << 2);         // tail start

    // Vectorized main: 4 elems/lane/iter, dwordx4 on both streams.
    // unroll 4 -> up to 8 independent dwordx4 in flight per thread.
#pragma unroll 4
    for (int g = tid; g < nvec; g += BLK) {
        const int j = p + (g << 2);
        const f4a s4 = __builtin_nontemporal_load((const f4a*)(arow + j));  // 16B aligned
        const f4u m4 = __builtin_nontemporal_load((const f4u*)(mrow + j));  // 4B aligned
        const bool o0 = (m4[0] != 0.0f);
        const bool o1 = (m4[1] != 0.0f);
        const bool o2 = (m4[2] != 0.0f);
        const bool o3 = (m4[3] != 0.0f);
        bc0 = fmaxf(bc0, o0 ? s4[0] : NEGF);
        sm0 = fmaxf(sm0, o0 ? NEGF : s4[0]);
        bc1 = fmaxf(bc1, o1 ? s4[1] : NEGF);
        sm1 = fmaxf(sm1, o1 ? NEGF : s4[1]);
        bc2 = fmaxf(bc2, o2 ? s4[2] : NEGF);
        sm2 = fmaxf(sm2, o2 ? NEGF : s4[2]);
        bc3 = fmaxf(bc3, o3 ? s4[3] : NEGF);
        sm3 = fmaxf(sm3, o3 ? NEGF : s4[3]);
    }
    // Scalar peel [0,p) and tail [t0,row): <=3 elems each.
    if (tid < p) {
        const float s = arow[tid], m = mrow[tid];
        if (m != 0.0f) bc0 = fmaxf(bc0, s); else sm0 = fmaxf(sm0, s);
    }
    if (tid < row - t0) {
        const int j = t0 + tid;
        const float s = arow[j], m = mrow[j];
        if (m != 0.0f) bc1 = fmaxf(bc1, s); else sm1 = fmaxf(sm1, s);
    }
    float bc = fmaxf(fmaxf(bc0, bc1), fmaxf(bc2, bc3));
    float sm = fmaxf(fmaxf(sm0, sm1), fmaxf(sm2, sm3));

    // Wave butterfly, then cross-wave LDS reduce.
    for (int off = 32; off; off >>= 1) {
        bc = fmaxf(bc, __shfl_down(bc, off));
        sm = fmaxf(sm, __shfl_down(sm, off));
    }
    __shared__ float r_bc[BLK / 64], r_sm[BLK / 64];
    if ((tid & 63) == 0) { r_bc[tid >> 6] = bc; r_sm[tid >> 6] = sm; }
    __syncthreads();
    if (tid == 0) {
        float B = r_bc[0], S = r_sm[0];
#pragma unroll
        for (int w = 1; w < BLK / 64; ++w) {
            B = fmaxf(B, r_bc[w]);
            S = fmaxf(S, r_sm[w]);
        }
        const float e = eps_scores[row];
        const float d = mrow[row];                 // diag of solution mask
        if (d != 0.0f) B = fmaxf(B, e);            // epsilon is a correct antecedent
        const float rc = d * link_costs[0] + (1.0f - d) * link_costs[1];
        float loss = fmaxf(0.0f, rc * (1.0f + S - B));
        if (d == 0.0f) loss = fmaxf(loss, false_new_cost[0] * (1.0f + e - B));
        out[row] = loss;
    }
}

extern "C" void kernel_launch(void* const* d_in, const int* in_sizes, int n_in,
                              void* d_out, int out_size, void* d_ws, size_t ws_size,
                              hipStream_t stream) {
    const float* eps  = (const float*)d_in[0];
    const float* ana  = (const float*)d_in[1];
    const float* mask = (const float*)d_in[2];
    const float* lc   = (const float*)d_in[3];
    const float* fnc  = (const float*)d_in[4];
    float* out = (float*)d_out;

    mention_loss_kernel<<<N, BLK, 0, stream>>>(eps, ana, mask, lc, fnc, out);
}

// Round 5
// 117.225 us; speedup vs baseline: 1.0541x; 1.0541x over previous
//
#include <hip/hip_runtime.h>

#define N 4096
#define BLK 256
#define NEGF (-3.4e38f)

// 4B-aligned float4 (multi-dword global loads need only dword alignment on CDNA).
typedef float f4u __attribute__((ext_vector_type(4), aligned(4)));
typedef float f4a __attribute__((ext_vector_type(4), aligned(16)));

// Single-pass, two running maxes per row (mask is exactly {0,1}):
//   bc = max over {m=1} of score     (ref's global min is dead code)
//   sm = max over {m=0, j<row} of ana score
//   loss = max(0, rc*(1+sm-bc), (d==0)*fn*(1+eps-bc))
// 4 independent accumulator pairs + branchless selects: no dependent fmax
// chain longer than nvec/BLK iterations per accumulator.
// NOTE (R4 A/B): __builtin_nontemporal_load on these streams costs ~6 us
// (mask stream is 4B-aligned; NT defeats L2 merging of line-straddling
// loads). Keep regular loads.
__global__ __launch_bounds__(BLK) void mention_loss_kernel(
    const float* __restrict__ eps_scores,
    const float* __restrict__ ana_scores,
    const float* __restrict__ mask,
    const float* __restrict__ link_costs,
    const float* __restrict__ false_new_cost,
    float* __restrict__ out)
{
    // Longest rows first: blockIdx 0 -> row N-1.
    const int row = N - 1 - (int)blockIdx.x;
    const int tid = threadIdx.x;
    const long long base = (long long)row * (row - 1) / 2;
    const float* __restrict__ arow = ana_scores + base;
    const float* __restrict__ mrow = mask + (size_t)row * (size_t)N;

    float bc0 = NEGF, bc1 = NEGF, bc2 = NEGF, bc3 = NEGF;
    float sm0 = NEGF, sm1 = NEGF, sm2 = NEGF, sm3 = NEGF;

    // Peel so ana_scores + base + p is 16B-aligned.
    int p = (int)((4 - (base & 3)) & 3);
    if (p > row) p = row;
    const int nvec = (row - p) >> 2;          // float4 groups in [p, p+4*nvec)
    const int t0   = p + (nvec << 2);         // tail start

    // Vectorized main: 4 elems/lane/iter, dwordx4 on both streams.
    // unroll 4 -> up to 8 independent dwordx4 in flight per thread.
#pragma unroll 4
    for (int g = tid; g < nvec; g += BLK) {
        const int j = p + (g << 2);
        const f4a s4 = *(const f4a*)(arow + j);   // 16B aligned
        const f4u m4 = *(const f4u*)(mrow + j);   // 4B aligned
        const bool o0 = (m4[0] != 0.0f);
        const bool o1 = (m4[1] != 0.0f);
        const bool o2 = (m4[2] != 0.0f);
        const bool o3 = (m4[3] != 0.0f);
        bc0 = fmaxf(bc0, o0 ? s4[0] : NEGF);
        sm0 = fmaxf(sm0, o0 ? NEGF : s4[0]);
        bc1 = fmaxf(bc1, o1 ? s4[1] : NEGF);
        sm1 = fmaxf(sm1, o1 ? NEGF : s4[1]);
        bc2 = fmaxf(bc2, o2 ? s4[2] : NEGF);
        sm2 = fmaxf(sm2, o2 ? NEGF : s4[2]);
        bc3 = fmaxf(bc3, o3 ? s4[3] : NEGF);
        sm3 = fmaxf(sm3, o3 ? NEGF : s4[3]);
    }
    // Scalar peel [0,p) and tail [t0,row): <=3 elems each.
    if (tid < p) {
        const float s = arow[tid], m = mrow[tid];
        if (m != 0.0f) bc0 = fmaxf(bc0, s); else sm0 = fmaxf(sm0, s);
    }
    if (tid < row - t0) {
        const int j = t0 + tid;
        const float s = arow[j], m = mrow[j];
        if (m != 0.0f) bc1 = fmaxf(bc1, s); else sm1 = fmaxf(sm1, s);
    }
    float bc = fmaxf(fmaxf(bc0, bc1), fmaxf(bc2, bc3));
    float sm = fmaxf(fmaxf(sm0, sm1), fmaxf(sm2, sm3));

    // Wave butterfly, then cross-wave LDS reduce.
    for (int off = 32; off; off >>= 1) {
        bc = fmaxf(bc, __shfl_down(bc, off));
        sm = fmaxf(sm, __shfl_down(sm, off));
    }
    __shared__ float r_bc[BLK / 64], r_sm[BLK / 64];
    if ((tid & 63) == 0) { r_bc[tid >> 6] = bc; r_sm[tid >> 6] = sm; }
    __syncthreads();
    if (tid == 0) {
        float B = r_bc[0], S = r_sm[0];
#pragma unroll
        for (int w = 1; w < BLK / 64; ++w) {
            B = fmaxf(B, r_bc[w]);
            S = fmaxf(S, r_sm[w]);
        }
        const float e = eps_scores[row];
        const float d = mrow[row];                 // diag of solution mask
        if (d != 0.0f) B = fmaxf(B, e);            // epsilon is a correct antecedent
        const float rc = d * link_costs[0] + (1.0f - d) * link_costs[1];
        float loss = fmaxf(0.0f, rc * (1.0f + S - B));
        if (d == 0.0f) loss = fmaxf(loss, false_new_cost[0] * (1.0f + e - B));
        out[row] = loss;
    }
}

extern "C" void kernel_launch(void* const* d_in, const int* in_sizes, int n_in,
                              void* d_out, int out_size, void* d_ws, size_t ws_size,
                              hipStream_t stream) {
    const float* eps  = (const float*)d_in[0];
    const float* ana  = (const float*)d_in[1];
    const float* mask = (const float*)d_in[2];
    const float* lc   = (const float*)d_in[3];
    const float* fnc  = (const float*)d_in[4];
    float* out = (float*)d_out;

    mention_loss_kernel<<<N, BLK, 0, stream>>>(eps, ana, mask, lc, fnc, out);
}